// Round 6
// baseline (313.399 us; speedup 1.0000x reference)
//
#include <hip/hip_runtime.h>
#include <hip/hip_bf16.h>

// Problem constants
#define BATCH 128
#define TSTEPS 64
#define EMB 256
#define HID 512
#define GATES 2048   // 4*HID
#define NFEAT 2048

typedef __bf16 bf16_t;
typedef __attribute__((ext_vector_type(8))) __bf16 bf16x8;
typedef __attribute__((ext_vector_type(4))) float f32x4;

#define MFMA16 __builtin_amdgcn_mfma_f32_16x16x32_bf16

// A/B fragment from row-major global: lane l -> row = row0 + (l&15), k = k0 + (l>>4)*8.
__device__ __forceinline__ bf16x8 frag16(const bf16_t* __restrict__ base, int row0, int stride,
                                         int k0, int lane) {
    return *(const bf16x8*)(base + (size_t)(row0 + (lane & 15)) * stride + k0 + ((lane >> 4) << 3));
}

__device__ __forceinline__ float sigm(float x) { return 1.f / (1.f + __expf(-x)); }
__device__ __forceinline__ float tanh_f(float x) { return 1.f - 2.f / (__expf(2.f * x) + 1.f); }

// System-scope (LLC-coherent, sc0sc1) ops — bypass L1/L2, no cache-invalidate fences.
__device__ __forceinline__ unsigned ld_sys(const unsigned* p) {
    return __hip_atomic_load(p, __ATOMIC_RELAXED, __HIP_MEMORY_SCOPE_SYSTEM);
}
__device__ __forceinline__ void st_sys(unsigned* p, unsigned v) {
    __hip_atomic_store(p, v, __ATOMIC_RELAXED, __HIP_MEMORY_SCOPE_SYSTEM);
}
// Two 16B LLC-bypass loads in flight, one wait.
__device__ __forceinline__ void ld2_sys_v4(const void* p0, const void* p1, uint4& a, uint4& b) {
    asm volatile("global_load_dwordx4 %0, %2, off sc0 sc1\n\t"
                 "global_load_dwordx4 %1, %3, off sc0 sc1\n\t"
                 "s_waitcnt vmcnt(0)"
                 : "=&v"(a), "=&v"(b)
                 : "v"(p0), "v"(p1)
                 : "memory");
}

__device__ __forceinline__ float bflo(unsigned w) {
    return __builtin_bit_cast(float, (w & 0xffffu) << 16);
}
__device__ __forceinline__ float bfhi(unsigned w) {
    return __builtin_bit_cast(float, w & 0xffff0000u);
}
__device__ __forceinline__ unsigned f2bf(float x) {
    return (unsigned)__builtin_bit_cast(unsigned short, (bf16_t)x);
}

// ---------------- prep: weights->bf16, bias sum, zero h0 (parity 0) + flags ----------------
__global__ __launch_bounds__(256) void k_prep(
    const float* __restrict__ Wih, const float* __restrict__ Whh, const float* __restrict__ Wout,
    const float* __restrict__ bih, const float* __restrict__ bhh,
    bf16_t* __restrict__ wih_b, bf16_t* __restrict__ whh_b, bf16_t* __restrict__ wout_b,
    float* __restrict__ biassum, bf16_t* __restrict__ h0, unsigned* __restrict__ wflag) {
    const int N1 = GATES * EMB;
    const int N2 = GATES * HID;
    const int N3 = NFEAT * HID;
    const int N4 = GATES;
    const int N5 = BATCH * HID;          // hbuf parity 0 = h_0 zero
    const int N6 = 1024;                 // wflag dwords
    const long total = (long)N1 + N2 + N3 + N4 + N5 + N6;
    for (long i = (long)blockIdx.x * blockDim.x + threadIdx.x; i < total;
         i += (long)gridDim.x * blockDim.x) {
        long x = i;
        if (x < N1) { wih_b[x] = (bf16_t)Wih[x]; continue; } x -= N1;
        if (x < N2) { whh_b[x] = (bf16_t)Whh[x]; continue; } x -= N2;
        if (x < N3) { wout_b[x] = (bf16_t)Wout[x]; continue; } x -= N3;
        if (x < N4) { biassum[x] = bih[x] + bhh[x]; continue; } x -= N4;
        if (x < N5) { h0[x] = (bf16_t)0.f; continue; } x -= N5;
        wflag[x] = 0u;
    }
}

// ---------------- x_proj GEMM with inline gather: one t per block-row ----------------
// Block (bx=t, by): rows t*128..+128 of xproj, cols by*128..+128. 4 waves (2x2), 64x64/wave.
// A-frags gathered from emb_tab on the fly (f32 -> bf16), tokens from m[b*T + t].
__global__ __launch_bounds__(256) void k_xproj(
    const int* __restrict__ m, const float* __restrict__ emb_tab,
    const bf16_t* __restrict__ Wih, const float* __restrict__ biassum,
    bf16_t* __restrict__ xproj) {     // [8192][2048] bf16, row = t*128+b
    int lane = threadIdx.x & 63, w = threadIdx.x >> 6;
    int t = blockIdx.x;                  // 0..63
    int b0 = (w >> 1) * 64;              // batch base for this wave
    int g0 = blockIdx.y * 128 + (w & 1) * 64;
    int q = lane >> 4;
    int tok[4];
    #pragma unroll
    for (int i = 0; i < 4; i++)
        tok[i] = m[(b0 + 16 * i + (lane & 15)) * TSTEPS + t];
    f32x4 acc[4][4] = {};
    #pragma unroll
    for (int k = 0; k < EMB; k += 32) {
        bf16x8 af[4], bf[4];
        #pragma unroll
        for (int i = 0; i < 4; i++) {
            const float* src = emb_tab + (size_t)tok[i] * EMB + k + q * 8;
            float4 lo = *(const float4*)(src);
            float4 hi = *(const float4*)(src + 4);
            bf16x8 v;
            v[0] = (bf16_t)lo.x; v[1] = (bf16_t)lo.y; v[2] = (bf16_t)lo.z; v[3] = (bf16_t)lo.w;
            v[4] = (bf16_t)hi.x; v[5] = (bf16_t)hi.y; v[6] = (bf16_t)hi.z; v[7] = (bf16_t)hi.w;
            af[i] = v;
        }
        #pragma unroll
        for (int j = 0; j < 4; j++) bf[j] = frag16(Wih, g0 + 16 * j, EMB, k, lane);
        #pragma unroll
        for (int i = 0; i < 4; i++)
            #pragma unroll
            for (int j = 0; j < 4; j++)
                acc[i][j] = MFMA16(af[i], bf[j], acc[i][j], 0, 0, 0);
    }
    #pragma unroll
    for (int j = 0; j < 4; j++) {
        int g = g0 + 16 * j + (lane & 15);
        float bs = biassum[g];
        #pragma unroll
        for (int i = 0; i < 4; i++)
            #pragma unroll
            for (int r = 0; r < 4; r++) {
                int row = t * BATCH + b0 + 16 * i + (q << 2) + r;
                xproj[(size_t)row * GATES + g] = (bf16_t)(acc[i][j][r] + bs);
            }
    }
}

// ---------------- recurrence: 64 blocks = 8 batch-groups x 8 hidden-strips ----------------
// Per-wave producer flags + direct wave polling + TRIPLE-buffered h (overwrite safety is
// implied by the staging polls: storing h_{t+1} overwrites h_{t-2}; flags >= t prove all
// group blocks finished step t-1, hence staged h_{t-2}). 2 barriers/step, no atomics/RMW.
// hbuf: [3 parity][8 group][16 kt][64 lane][8 bf16] (h_t in parity t%3).
// wflag: [8 group][8 strip][16 dwords] (only [0..7] used; 64B spacing).
__global__ __launch_bounds__(512, 1) void k_rnn(
    const bf16_t* __restrict__ xp,    // [8192][2048] bf16
    const bf16_t* __restrict__ whh,   // [2048][512] bf16
    bf16_t* __restrict__ hbuf,
    unsigned* __restrict__ wflag) {
    __shared__ __align__(16) char hstage[16384];   // [16 kt][64 lane][16B]
    __shared__ float gex[4][16][66];               // gate exchange
    const int tid = threadIdx.x;
    const int lane = tid & 63, w = tid >> 6;
    const int group = blockIdx.x >> 3;      // 0..7
    const int s     = blockIdx.x & 7;       // 0..7
    const int g = w >> 1, hh = w & 1;

    // --- preload Whh slice into registers and pin ---
    bf16x8 Bf0[16], Bf1[16];
    {
        const bf16_t* wb = whh + (size_t)(g * HID + s * 64 + hh * 32) * HID;
        #pragma unroll
        for (int kt = 0; kt < 16; ++kt) {
            Bf0[kt] = frag16(wb, 0, HID, kt * 32, lane);
            Bf1[kt] = frag16(wb, 16, HID, kt * 32, lane);
        }
        #pragma unroll
        for (int kt = 0; kt < 16; ++kt)
            asm volatile("" : "+v"(Bf0[kt]), "+v"(Bf1[kt]));
    }

    const int r_up = tid >> 5;              // 0..15 (batch row within group)
    const int c0 = (tid & 31) * 2;          // 0..62 (local col pair)
    float cst0 = 0.f, cst1 = 0.f;           // cell state

    // Consumer: thread stages chunks tid and tid+512 -> producer strips w>>1 and (w>>1)+4.
    // Lanes 0-7 poll strip w>>1's 8 wave-flags, lanes 8-15 poll strip (w>>1)+4's.
    const int sPoll = (w >> 1) + ((lane & 8) ? 4 : 0);
    const unsigned* pf = wflag + (((group << 3) + sPoll) << 4) + (lane & 7);
    unsigned* myflag = wflag + (((group << 3) + s) << 4) + w;

    // h-store position (fragment layout), in dword units; parity stride = 32768 dwords
    unsigned* hst;
    {
        int j = s * 64 + c0;
        int kt = j >> 5;
        int lane_p = (((j & 31) >> 3) << 4) | r_up;
        hst = (unsigned*)hbuf + (size_t)group * 4096 + kt * 256 + lane_p * 4 + ((j & 7) >> 1);
    }

    int parS = 0;   // parity holding h_t
    for (int t = 0; t < TSTEPS; ++t) {
        // xproj prefetch (independent of h; latency hides under poll)
        unsigned xw0, xw1, xw2, xw3;
        {
            const bf16_t* xrow = xp + ((size_t)t * BATCH + group * 16 + r_up) * GATES + s * 64 + c0;
            xw0 = *(const unsigned*)(xrow);
            xw1 = *(const unsigned*)(xrow + HID);
            xw2 = *(const unsigned*)(xrow + 2 * HID);
            xw3 = *(const unsigned*)(xrow + 3 * HID);
        }

        if (t) {   // wait for this thread's two producer strips (wave-granular arrival)
            unsigned v;
            do { v = ld_sys(pf); } while (!__all((int)(v >= (unsigned)t)));
        }

        // --- stage h_t: pure 16B copies LLC -> LDS (fragment layout) ---
        {
            const char* gsrc = (const char*)hbuf + (size_t)parS * 131072 + (size_t)group * 16384;
            uint4 va, vb;
            ld2_sys_v4(gsrc + (size_t)tid * 16, gsrc + (size_t)(tid + 512) * 16, va, vb);
            *(uint4*)(hstage + (size_t)tid * 16) = va;
            *(uint4*)(hstage + (size_t)(tid + 512) * 16) = vb;
        }
        __syncthreads();   // B1: LDS h ready (also: all staging polls passed -> store-safety)

        // --- gates GEMM: 16 rows x 32 cols, K=512, B in registers ---
        f32x4 a0 = {}, a1 = {};
        {
            const bf16_t* hs = (const bf16_t*)hstage;
            #pragma unroll
            for (int kt = 0; kt < 16; ++kt) {
                bf16x8 a = *(const bf16x8*)(hs + kt * 512 + lane * 8);
                a0 = MFMA16(a, Bf0[kt], a0, 0, 0, 0);
                a1 = MFMA16(a, Bf1[kt], a1, 0, 0, 0);
            }
        }

        // --- gate exchange via LDS ---
        {
            const int jj = lane & 15, q = lane >> 4;
            #pragma unroll
            for (int rr = 0; rr < 4; ++rr) {
                gex[g][q * 4 + rr][hh * 32 + jj]      = a0[rr];
                gex[g][q * 4 + rr][hh * 32 + 16 + jj] = a1[rr];
            }
        }
        __syncthreads();   // B2: gex ready; hstage free for next staging

        // --- cell update (2 cells/thread) + h store to LLC + per-wave flag ---
        {
            float2 gi = *(const float2*)&gex[0][r_up][c0];
            float2 gf = *(const float2*)&gex[1][r_up][c0];
            float2 gg = *(const float2*)&gex[2][r_up][c0];
            float2 go = *(const float2*)&gex[3][r_up][c0];
            float iv0 = gi.x + bflo(xw0), iv1 = gi.y + bfhi(xw0);
            float fv0 = gf.x + bflo(xw1), fv1 = gf.y + bfhi(xw1);
            float gv0 = gg.x + bflo(xw2), gv1 = gg.y + bfhi(xw2);
            float ov0 = go.x + bflo(xw3), ov1 = go.y + bfhi(xw3);
            cst0 = sigm(fv0) * cst0 + sigm(iv0) * tanh_f(gv0);
            cst1 = sigm(fv1) * cst1 + sigm(iv1) * tanh_f(gv1);
            float h0v = sigm(ov0) * tanh_f(cst0);
            float h1v = sigm(ov1) * tanh_f(cst1);
            unsigned pack = f2bf(h0v) | (f2bf(h1v) << 16);
            int parD = parS + 1; if (parD == 3) parD = 0;
            st_sys(hst + (size_t)parD * 32768, pack);
            asm volatile("s_waitcnt vmcnt(0)" ::: "memory");   // wave's stores at LLC
            if (lane == 0) st_sys(myflag, (unsigned)(t + 1));
            parS = parD;
        }
    }
}

// A-frag from hbuf fragment-piece layout [group][16 kt][64 lane][8]
__device__ __forceinline__ bf16x8 frag_piece(const bf16_t* hb, int group, int kt, int lane) {
    return *(const bf16x8*)(hb + (size_t)group * 8192 + kt * 512 + lane * 8);
}

// ---------------- output GEMM: h[128,512] x Wout^T + b_out -> out f32 [128][2048] ------------
__global__ __launch_bounds__(256) void k_out(
    const bf16_t* __restrict__ h,      // hbuf parity 1 (h_64), fragment-piece layout
    const bf16_t* __restrict__ Wout,
    const float* __restrict__ bout,
    float* __restrict__ out) {
    int lane = threadIdx.x & 63, w = threadIdx.x >> 6;
    int r0 = blockIdx.x * 32 + (w & 1) * 16;
    int g0 = blockIdx.y * 128 + (w >> 1) * 64;
    int group = r0 >> 4;
    f32x4 acc[4] = {};
    #pragma unroll 4
    for (int kt = 0; kt < 16; ++kt) {
        bf16x8 a = frag_piece(h, group, kt, lane);
        #pragma unroll
        for (int t = 0; t < 4; t++) {
            bf16x8 b = frag16(Wout, g0 + 16 * t, HID, kt * 32, lane);
            acc[t] = MFMA16(a, b, acc[t], 0, 0, 0);
        }
    }
    #pragma unroll
    for (int t = 0; t < 4; t++) {
        int g = g0 + 16 * t + (lane & 15);
        float bs = bout[g];
        #pragma unroll
        for (int r = 0; r < 4; r++) {
            int row = r0 + ((lane >> 4) << 2) + r;
            out[(size_t)row * NFEAT + g] = acc[t][r] + bs;
        }
    }
}

extern "C" void kernel_launch(void* const* d_in, const int* in_sizes, int n_in,
                              void* d_out, int out_size, void* d_ws, size_t ws_size,
                              hipStream_t stream) {
    const int*   m       = (const int*)d_in[0];
    // d_in[1] = images (unused by reference)
    const float* emb_tab = (const float*)d_in[2];
    const float* W_ih    = (const float*)d_in[3];
    const float* W_hh    = (const float*)d_in[4];
    const float* b_ih    = (const float*)d_in[5];
    const float* b_hh    = (const float*)d_in[6];
    const float* W_out   = (const float*)d_in[7];
    const float* b_out   = (const float*)d_in[8];

    char* ws = (char*)d_ws;
    bf16_t*   xpb     = (bf16_t*)  (ws + 0);          // 8192*2048*2 = 33554432
    bf16_t*   wih_b   = (bf16_t*)  (ws + 33554432);   // 1048576
    bf16_t*   whh_b   = (bf16_t*)  (ws + 34603008);   // 2097152
    bf16_t*   wout_b  = (bf16_t*)  (ws + 36700160);   // 2097152
    bf16_t*   hbuf    = (bf16_t*)  (ws + 38797312);   // 3*131072 = 393216
    float*    biassum = (float*)   (ws + 39190528);   // 8192
    unsigned* wflag   = (unsigned*)(ws + 39198720);   // 4096

    k_prep<<<dim3(1024), dim3(256), 0, stream>>>(W_ih, W_hh, W_out, b_ih, b_hh,
                                                 wih_b, whh_b, wout_b, biassum,
                                                 hbuf /*parity 0 = h_0*/, wflag);

    k_xproj<<<dim3(64, 16), dim3(256), 0, stream>>>(m, emb_tab, wih_b, biassum, xpb);

    k_rnn<<<dim3(64), dim3(512), 0, stream>>>(xpb, whh_b, hbuf, wflag);

    // h_64 lives in parity 64%3 = 1
    k_out<<<dim3(4, 16), dim3(256), 0, stream>>>(hbuf + 65536, wout_b, b_out, (float*)d_out);
}

// Round 7
// 290.991 us; speedup vs baseline: 1.0770x; 1.0770x over previous
//
#include <hip/hip_runtime.h>
#include <hip/hip_bf16.h>

// Problem constants
#define BATCH 128
#define TSTEPS 64
#define EMB 256
#define HID 512
#define GATES 2048   // 4*HID
#define NFEAT 2048

typedef __bf16 bf16_t;
typedef __attribute__((ext_vector_type(8))) __bf16 bf16x8;
typedef __attribute__((ext_vector_type(4))) float f32x4;

#define MFMA16 __builtin_amdgcn_mfma_f32_16x16x32_bf16

// A/B fragment from row-major global: lane l -> row = row0 + (l&15), k = k0 + (l>>4)*8.
__device__ __forceinline__ bf16x8 frag16(const bf16_t* __restrict__ base, int row0, int stride,
                                         int k0, int lane) {
    return *(const bf16x8*)(base + (size_t)(row0 + (lane & 15)) * stride + k0 + ((lane >> 4) << 3));
}

__device__ __forceinline__ float sigm(float x) { return 1.f / (1.f + __expf(-x)); }
__device__ __forceinline__ float tanh_f(float x) { return 1.f - 2.f / (__expf(2.f * x) + 1.f); }

// ---- LLC-coherent (sc0sc1) primitives: bypass L1/L2, never invalidate caches ----
// 4x 16B loads in flight, one wait (poll + stage in one shot).
__device__ __forceinline__ void ld4_sys_v4(const void* p0, const void* p1,
                                           const void* p2, const void* p3,
                                           uint4& a, uint4& b, uint4& c, uint4& d) {
    asm volatile("global_load_dwordx4 %0, %4, off sc0 sc1\n\t"
                 "global_load_dwordx4 %1, %5, off sc0 sc1\n\t"
                 "global_load_dwordx4 %2, %6, off sc0 sc1\n\t"
                 "global_load_dwordx4 %3, %7, off sc0 sc1\n\t"
                 "s_waitcnt vmcnt(0)"
                 : "=&v"(a), "=&v"(b), "=&v"(c), "=&v"(d)
                 : "v"(p0), "v"(p1), "v"(p2), "v"(p3)
                 : "memory");
}
// single 8B store (data + tag), fire-and-forget
__device__ __forceinline__ void st_sys_v2(void* p, unsigned lo, unsigned hi) {
    uint2 v = make_uint2(lo, hi);
    asm volatile("global_store_dwordx2 %0, %1, off sc0 sc1" :: "v"(p), "v"(v) : "memory");
}

__device__ __forceinline__ float bflo(unsigned w) {
    return __builtin_bit_cast(float, (w & 0xffffu) << 16);
}
__device__ __forceinline__ float bfhi(unsigned w) {
    return __builtin_bit_cast(float, w & 0xffff0000u);
}
__device__ __forceinline__ unsigned f2bf(float x) {
    return (unsigned)__builtin_bit_cast(unsigned short, (bf16_t)x);
}

// ---------------- prep: weights->bf16, bias sum, zero h0 packets (parity 0) ----------------
__global__ __launch_bounds__(256) void k_prep(
    const float* __restrict__ Wih, const float* __restrict__ Whh, const float* __restrict__ Wout,
    const float* __restrict__ bih, const float* __restrict__ bhh,
    bf16_t* __restrict__ wih_b, bf16_t* __restrict__ whh_b, bf16_t* __restrict__ wout_b,
    float* __restrict__ biassum, unsigned long long* __restrict__ pkt0) {
    const int N1 = GATES * EMB;
    const int N2 = GATES * HID;
    const int N3 = NFEAT * HID;
    const int N4 = GATES;
    const int N5 = 32768;                // parity-0 packets {h=0, tag=0}
    const long total = (long)N1 + N2 + N3 + N4 + N5;
    for (long i = (long)blockIdx.x * blockDim.x + threadIdx.x; i < total;
         i += (long)gridDim.x * blockDim.x) {
        long x = i;
        if (x < N1) { wih_b[x] = (bf16_t)Wih[x]; continue; } x -= N1;
        if (x < N2) { whh_b[x] = (bf16_t)Whh[x]; continue; } x -= N2;
        if (x < N3) { wout_b[x] = (bf16_t)Wout[x]; continue; } x -= N3;
        if (x < N4) { biassum[x] = bih[x] + bhh[x]; continue; } x -= N4;
        pkt0[x] = 0ull;
    }
}

// ---------------- x_proj GEMM with inline gather: one t per block-row ----------------
__global__ __launch_bounds__(256) void k_xproj(
    const int* __restrict__ m, const float* __restrict__ emb_tab,
    const bf16_t* __restrict__ Wih, const float* __restrict__ biassum,
    bf16_t* __restrict__ xproj) {     // [8192][2048] bf16, row = t*128+b
    int lane = threadIdx.x & 63, w = threadIdx.x >> 6;
    int t = blockIdx.x;                  // 0..63
    int b0 = (w >> 1) * 64;              // batch base for this wave
    int g0 = blockIdx.y * 128 + (w & 1) * 64;
    int q = lane >> 4;
    int tok[4];
    #pragma unroll
    for (int i = 0; i < 4; i++)
        tok[i] = m[(b0 + 16 * i + (lane & 15)) * TSTEPS + t];
    f32x4 acc[4][4] = {};
    #pragma unroll
    for (int k = 0; k < EMB; k += 32) {
        bf16x8 af[4], bf[4];
        #pragma unroll
        for (int i = 0; i < 4; i++) {
            const float* src = emb_tab + (size_t)tok[i] * EMB + k + q * 8;
            float4 lo = *(const float4*)(src);
            float4 hi = *(const float4*)(src + 4);
            bf16x8 v;
            v[0] = (bf16_t)lo.x; v[1] = (bf16_t)lo.y; v[2] = (bf16_t)lo.z; v[3] = (bf16_t)lo.w;
            v[4] = (bf16_t)hi.x; v[5] = (bf16_t)hi.y; v[6] = (bf16_t)hi.z; v[7] = (bf16_t)hi.w;
            af[i] = v;
        }
        #pragma unroll
        for (int j = 0; j < 4; j++) bf[j] = frag16(Wih, g0 + 16 * j, EMB, k, lane);
        #pragma unroll
        for (int i = 0; i < 4; i++)
            #pragma unroll
            for (int j = 0; j < 4; j++)
                acc[i][j] = MFMA16(af[i], bf[j], acc[i][j], 0, 0, 0);
    }
    #pragma unroll
    for (int j = 0; j < 4; j++) {
        int g = g0 + 16 * j + (lane & 15);
        float bs = biassum[g];
        #pragma unroll
        for (int i = 0; i < 4; i++)
            #pragma unroll
            for (int r = 0; r < 4; r++) {
                int row = t * BATCH + b0 + 16 * i + (q << 2) + r;
                xproj[(size_t)row * GATES + g] = (bf16_t)(acc[i][j][r] + bs);
            }
    }
}

// ---------------- recurrence: 64 blocks = 8 batch-groups x 8 hidden-strips ----------------
// h exchanged as tagged 8B packets {2xbf16, tag=t}: the store IS the signal, the poll IS the
// stage load. No flags, no RMW, no vmcnt drain on the producer side. Double-buffered by step
// parity; safety: a block stores tag t+2 into a slot only after every block of its group fully
// staged tag t (its own staging proves all stored h_{t+1}, which proves all staged h_t).
// Packet layout per parity: [8 group][1024 chunk][4 pkt]; chunk c <-> frag bytes [c*16,c*16+16)
// of the group's [16 kt][64 lane][16B] fragment image.
__global__ __launch_bounds__(512, 1) void k_rnn(
    const bf16_t* __restrict__ xp,    // [8192][2048] bf16
    const bf16_t* __restrict__ whh,   // [2048][512] bf16
    char* __restrict__ hbuf,          // packets: 2 parity x 256KB
    bf16_t* __restrict__ hfin) {      // dense frag image of h_64 (for k_out)
    __shared__ __align__(16) char hstage[16384];   // [16 kt][64 lane][16B]
    __shared__ float gex[4][16][66];               // gate exchange
    const int tid = threadIdx.x;
    const int lane = tid & 63, w = tid >> 6;
    const int group = blockIdx.x >> 3;      // 0..7
    const int s     = blockIdx.x & 7;       // 0..7
    const int g = w >> 1, hh = w & 1;

    // --- preload Whh slice into registers and pin ---
    bf16x8 Bf0[16], Bf1[16];
    {
        const bf16_t* wb = whh + (size_t)(g * HID + s * 64 + hh * 32) * HID;
        #pragma unroll
        for (int kt = 0; kt < 16; ++kt) {
            Bf0[kt] = frag16(wb, 0, HID, kt * 32, lane);
            Bf1[kt] = frag16(wb, 16, HID, kt * 32, lane);
        }
        #pragma unroll
        for (int kt = 0; kt < 16; ++kt)
            asm volatile("" : "+v"(Bf0[kt]), "+v"(Bf1[kt]));
    }

    const int r_up = tid >> 5;              // 0..15 (batch row within group)
    const int c0 = (tid & 31) * 2;          // 0..62 (local col pair)
    float cst0 = 0.f, cst1 = 0.f;           // cell state

    // producer packet byte offset (within a parity region)
    size_t pk_off;
    int fin_idx;
    {
        int j = s * 64 + c0;
        int kt = j >> 5;
        int lane_p = (((j & 31) >> 3) << 4) | r_up;
        int dw = kt * 256 + lane_p * 4 + ((j & 7) >> 1);   // frag dword index 0..4095
        pk_off = (size_t)group * 32768 + (size_t)dw * 8;
        fin_idx = dw;                                       // dword index into group's dense image
    }
    // consumer packet pointers (cover chunks tid and tid+512)
    const char* q0base = hbuf + (size_t)group * 32768 + (size_t)tid * 32;
    const char* q2base = hbuf + (size_t)group * 32768 + (size_t)(tid + 512) * 32;

    int parS = 0;   // parity holding h_t packets
    for (int t = 0; t < TSTEPS; ++t) {
        // xproj prefetch (independent of h; latency hides under poll)
        unsigned xw0, xw1, xw2, xw3;
        {
            const bf16_t* xrow = xp + ((size_t)t * BATCH + group * 16 + r_up) * GATES + s * 64 + c0;
            xw0 = *(const unsigned*)(xrow);
            xw1 = *(const unsigned*)(xrow + HID);
            xw2 = *(const unsigned*)(xrow + 2 * HID);
            xw3 = *(const unsigned*)(xrow + 3 * HID);
        }

        // --- poll+stage h_t: tagged packets, LLC -> regs -> LDS ---
        {
            const char* q0 = q0base + (size_t)parS * 262144;
            const char* q2 = q2base + (size_t)parS * 262144;
            const unsigned tg = (unsigned)t;
            uint4 a, b, c, d;
            do {
                ld4_sys_v4(q0, q0 + 16, q2, q2 + 16, a, b, c, d);
            } while (!__all((int)(a.y == tg && a.w == tg && b.y == tg && b.w == tg &&
                                  c.y == tg && c.w == tg && d.y == tg && d.w == tg)));
            *(uint4*)(hstage + (size_t)tid * 16)         = make_uint4(a.x, a.z, b.x, b.z);
            *(uint4*)(hstage + (size_t)(tid + 512) * 16) = make_uint4(c.x, c.z, d.x, d.z);
        }
        __syncthreads();   // B1: LDS h ready

        // --- gates GEMM: 16 rows x 32 cols, K=512, B in registers ---
        f32x4 a0 = {}, a1 = {};
        {
            const bf16_t* hs = (const bf16_t*)hstage;
            #pragma unroll
            for (int kt = 0; kt < 16; ++kt) {
                bf16x8 a = *(const bf16x8*)(hs + kt * 512 + lane * 8);
                a0 = MFMA16(a, Bf0[kt], a0, 0, 0, 0);
                a1 = MFMA16(a, Bf1[kt], a1, 0, 0, 0);
            }
        }

        // --- gate exchange via LDS ---
        {
            const int jj = lane & 15, q = lane >> 4;
            #pragma unroll
            for (int rr = 0; rr < 4; ++rr) {
                gex[g][q * 4 + rr][hh * 32 + jj]      = a0[rr];
                gex[g][q * 4 + rr][hh * 32 + 16 + jj] = a1[rr];
            }
        }
        __syncthreads();   // B2: gex ready; hstage free for next step's staging

        // --- cell update (2 cells/thread) + tagged packet store (fire-and-forget) ---
        {
            float2 gi = *(const float2*)&gex[0][r_up][c0];
            float2 gf = *(const float2*)&gex[1][r_up][c0];
            float2 gg = *(const float2*)&gex[2][r_up][c0];
            float2 go = *(const float2*)&gex[3][r_up][c0];
            float iv0 = gi.x + bflo(xw0), iv1 = gi.y + bfhi(xw0);
            float fv0 = gf.x + bflo(xw1), fv1 = gf.y + bfhi(xw1);
            float gv0 = gg.x + bflo(xw2), gv1 = gg.y + bfhi(xw2);
            float ov0 = go.x + bflo(xw3), ov1 = go.y + bfhi(xw3);
            cst0 = sigm(fv0) * cst0 + sigm(iv0) * tanh_f(gv0);
            cst1 = sigm(fv1) * cst1 + sigm(iv1) * tanh_f(gv1);
            float h0v = sigm(ov0) * tanh_f(cst0);
            float h1v = sigm(ov1) * tanh_f(cst1);
            unsigned pack = f2bf(h0v) | (f2bf(h1v) << 16);
            int parD = parS ^ 1;
            st_sys_v2(hbuf + (size_t)parD * 262144 + pk_off, pack, (unsigned)(t + 1));
            if (t == TSTEPS - 1)
                *((unsigned*)hfin + (size_t)group * 4096 + fin_idx) = pack;
            parS = parD;
        }
    }
}

// A-frag from dense fragment image [group][16 kt][64 lane][8]
__device__ __forceinline__ bf16x8 frag_piece(const bf16_t* hb, int group, int kt, int lane) {
    return *(const bf16x8*)(hb + (size_t)group * 8192 + kt * 512 + lane * 8);
}

// ---------------- output GEMM: h[128,512] x Wout^T + b_out -> out f32 [128][2048] ------------
__global__ __launch_bounds__(256) void k_out(
    const bf16_t* __restrict__ h,      // hfin dense frag image
    const bf16_t* __restrict__ Wout,
    const float* __restrict__ bout,
    float* __restrict__ out) {
    int lane = threadIdx.x & 63, w = threadIdx.x >> 6;
    int r0 = blockIdx.x * 32 + (w & 1) * 16;
    int g0 = blockIdx.y * 128 + (w >> 1) * 64;
    int group = r0 >> 4;
    f32x4 acc[4] = {};
    #pragma unroll 4
    for (int kt = 0; kt < 16; ++kt) {
        bf16x8 a = frag_piece(h, group, kt, lane);
        #pragma unroll
        for (int t = 0; t < 4; t++) {
            bf16x8 b = frag16(Wout, g0 + 16 * t, HID, kt * 32, lane);
            acc[t] = MFMA16(a, b, acc[t], 0, 0, 0);
        }
    }
    #pragma unroll
    for (int t = 0; t < 4; t++) {
        int g = g0 + 16 * t + (lane & 15);
        float bs = bout[g];
        #pragma unroll
        for (int r = 0; r < 4; r++) {
            int row = r0 + ((lane >> 4) << 2) + r;
            out[(size_t)row * NFEAT + g] = acc[t][r] + bs;
        }
    }
}

extern "C" void kernel_launch(void* const* d_in, const int* in_sizes, int n_in,
                              void* d_out, int out_size, void* d_ws, size_t ws_size,
                              hipStream_t stream) {
    const int*   m       = (const int*)d_in[0];
    // d_in[1] = images (unused by reference)
    const float* emb_tab = (const float*)d_in[2];
    const float* W_ih    = (const float*)d_in[3];
    const float* W_hh    = (const float*)d_in[4];
    const float* b_ih    = (const float*)d_in[5];
    const float* b_hh    = (const float*)d_in[6];
    const float* W_out   = (const float*)d_in[7];
    const float* b_out   = (const float*)d_in[8];

    char* ws = (char*)d_ws;
    bf16_t* xpb     = (bf16_t*)(ws + 0);          // 8192*2048*2 = 33554432
    bf16_t* wih_b   = (bf16_t*)(ws + 33554432);   // 1048576
    bf16_t* whh_b   = (bf16_t*)(ws + 34603008);   // 2097152
    bf16_t* wout_b  = (bf16_t*)(ws + 36700160);   // 2097152
    char*   hbuf    = (char*)  (ws + 38797312);   // packets 2*262144 = 524288
    bf16_t* hfin    = (bf16_t*)(ws + 39321600);   // 131072
    float*  biassum = (float*) (ws + 39452672);   // 8192

    k_prep<<<dim3(1024), dim3(256), 0, stream>>>(W_ih, W_hh, W_out, b_ih, b_hh,
                                                 wih_b, whh_b, wout_b, biassum,
                                                 (unsigned long long*)hbuf);

    k_xproj<<<dim3(64, 16), dim3(256), 0, stream>>>(m, emb_tab, wih_b, biassum, xpb);

    k_rnn<<<dim3(64), dim3(512), 0, stream>>>(xpb, whh_b, hbuf, hfin);

    k_out<<<dim3(4, 16), dim3(256), 0, stream>>>(hfin, wout_b, b_out, (float*)d_out);
}